// Round 12
// baseline (123.617 us; speedup 1.0000x reference)
//
#include <hip/hip_runtime.h>

#define NROWS 131072          // 64*2048
#define D 64
#define K 512
#define TPB 256               // 4 waves/block
#define RPB 256               // 4 waves x 64 rows each
#define NBLK (NROWS/RPB)      // 512 blocks, 2048 waves total = 2/SIMD, all resident

#define LOSS_OFF (NROWS*D)    // 8388608
#define PERP_OFF (LOSS_OFF+1)
#define IDX_OFF  (LOSS_OFF+2)

typedef short  s16x8 __attribute__((ext_vector_type(8)));   // 8 bf16 (4 VGPR)
typedef float  f32x4 __attribute__((ext_vector_type(4)));   // MFMA acc

// ws: [0] f32 wsum | [256B] int hist[512] | [4096B] f32 e2[512] | [8192B] bfrag 196608B

// exact 3-way bf16 split of 8 floats (mask-truncate: hi+mid+lo = top 24 mantissa bits)
__device__ __forceinline__ void split8(float4 a, float4 b,
                                       s16x8* h8, s16x8* m8, s16x8* l8)
{
    float xf[8] = {a.x,a.y,a.z,a.w,b.x,b.y,b.z,b.w};
    short hh[8], mm[8], ll[8];
    #pragma unroll
    for (int j = 0; j < 8; ++j) {
        float x = xf[j];
        unsigned uh = __float_as_uint(x) & 0xFFFF0000u;
        float rh = x - __uint_as_float(uh);            // exact
        unsigned um = __float_as_uint(rh) & 0xFFFF0000u;
        float rm = rh - __uint_as_float(um);           // exact
        unsigned ul = __float_as_uint(rm) & 0xFFFF0000u;
        hh[j] = (short)(uh >> 16);
        mm[j] = (short)(um >> 16);
        ll[j] = (short)(ul >> 16);
    }
    *h8 = (s16x8){hh[0],hh[1],hh[2],hh[3],hh[4],hh[5],hh[6],hh[7]};
    *m8 = (s16x8){mm[0],mm[1],mm[2],mm[3],mm[4],mm[5],mm[6],mm[7]};
    *l8 = (s16x8){ll[0],ll[1],ll[2],ll[3],ll[4],ll[5],ll[6],ll[7]};
}

// prep: pack (-2*codebook) splits into MFMA B-fragment order + e2 norms.
// (-2x is exact: sign flip + exponent+1 commute with bf16 mask-truncation.)
__global__ __launch_bounds__(64) void vq_prep(
    const float* __restrict__ emb, float* __restrict__ e2, s16x8* __restrict__ bfrag)
{
    const int ct = blockIdx.x, l = threadIdx.x;      // 32 blocks x 64
    const int q = l >> 4, r16 = l & 15;
    const int code = ct*16 + r16;
    const float4* e4 = reinterpret_cast<const float4*>(emb + (size_t)code * D);
    #pragma unroll
    for (int s = 0; s < 2; ++s) {
        float4 f0 = e4[q*2 + s*8];
        float4 f1 = e4[q*2 + s*8 + 1];
        float4 g0 = {-2.f*f0.x, -2.f*f0.y, -2.f*f0.z, -2.f*f0.w};
        float4 g1 = {-2.f*f1.x, -2.f*f1.y, -2.f*f1.z, -2.f*f1.w};
        s16x8 h, m, lo;
        split8(g0, g1, &h, &m, &lo);
        bfrag[(ct*6 + 0 + s)*64 + l] = h;    // hi chunk, kstep s
        bfrag[(ct*6 + 2 + s)*64 + l] = m;    // mid
        bfrag[(ct*6 + 4 + s)*64 + l] = lo;   // lo
    }
    if (l < 16) {
        const float* e = emb + (size_t)(ct*16 + l) * D;
        float s0=0.f,s1=0.f,s2=0.f,s3=0.f;
        #pragma unroll
        for (int d = 0; d < D; d += 4) {
            s0 = fmaf(e[d+0], e[d+0], s0);
            s1 = fmaf(e[d+1], e[d+1], s1);
            s2 = fmaf(e[d+2], e[d+2], s2);
            s3 = fmaf(e[d+3], e[d+3], s3);
        }
        e2[ct*16 + l] = (s0+s1)+(s2+s3);
    }
}

#define MFMA_(AV, BV, CI) __builtin_amdgcn_mfma_f32_16x16x32_bf16((AV), (BV), (CI), 0, 0, 0)

// load B-fragment set for tile CT into named regs (stay in flight)
#define LOADB(B00,B01,B10,B11,B20,B21,E2V, CT) do {                 \
    const s16x8* _bp = bbase + (size_t)(CT)*6*64;                   \
    B00 = _bp[0*64]; B01 = _bp[1*64];                               \
    B10 = _bp[2*64]; B11 = _bp[3*64];                               \
    B20 = _bp[4*64]; B21 = _bp[5*64];                               \
    E2V = e2g[((CT) << 4) + r16];                                   \
} while (0)

// 48 MFMAs for one tile: 4 row-frags (mt) x {S0 chain seeded e2, S1 chain seeded 0}.
// 8 independent acc chains, dependency distance >= 4 MFMAs.
#define TILE_MFMA_ALL(B00,B01,B10,B11,B20,B21, E2V) do {                          \
    f32x4 _ci = {(E2V),(E2V),(E2V),(E2V)};                                        \
    _Pragma("unroll") for (int mt=0; mt<4; ++mt) accS0[mt] = MFMA_(Af[mt][0][0], B00, _ci);      \
    _Pragma("unroll") for (int mt=0; mt<4; ++mt) accS1[mt] = MFMA_(Af[mt][0][0], B10, zero4);    \
    _Pragma("unroll") for (int mt=0; mt<4; ++mt) accS0[mt] = MFMA_(Af[mt][0][1], B01, accS0[mt]);\
    _Pragma("unroll") for (int mt=0; mt<4; ++mt) accS1[mt] = MFMA_(Af[mt][0][1], B11, accS1[mt]);\
    _Pragma("unroll") for (int mt=0; mt<4; ++mt) accS0[mt] = MFMA_(Af[mt][1][0], B00, accS0[mt]);\
    _Pragma("unroll") for (int mt=0; mt<4; ++mt) accS1[mt] = MFMA_(Af[mt][0][0], B20, accS1[mt]);\
    _Pragma("unroll") for (int mt=0; mt<4; ++mt) accS0[mt] = MFMA_(Af[mt][1][1], B01, accS0[mt]);\
    _Pragma("unroll") for (int mt=0; mt<4; ++mt) accS1[mt] = MFMA_(Af[mt][0][1], B21, accS1[mt]);\
    _Pragma("unroll") for (int mt=0; mt<4; ++mt) accS0[mt] = MFMA_(Af[mt][2][0], B00, accS0[mt]);\
    _Pragma("unroll") for (int mt=0; mt<4; ++mt) accS1[mt] = MFMA_(Af[mt][1][0], B10, accS1[mt]);\
    _Pragma("unroll") for (int mt=0; mt<4; ++mt) accS0[mt] = MFMA_(Af[mt][2][1], B01, accS0[mt]);\
    _Pragma("unroll") for (int mt=0; mt<4; ++mt) accS1[mt] = MFMA_(Af[mt][1][1], B11, accS1[mt]);\
} while (0)

// running argmin over the finished acc sets
#define TILE_ARGMIN_ALL(CT) do {                                             \
    const int _col = ((CT) << 4) + r16;                                      \
    _Pragma("unroll")                                                        \
    for (int mt = 0; mt < 4; ++mt)                                           \
        _Pragma("unroll")                                                    \
        for (int g = 0; g < 4; ++g) {                                        \
            float dst = accS0[mt][g] + accS1[mt][g];                         \
            if (dst < bestd[mt][g]) { bestd[mt][g] = dst; besti[mt][g] = _col; } \
        }                                                                    \
} while (0)

__global__ __launch_bounds__(TPB, 1) void vq_main(
    const float* __restrict__ x, const float* __restrict__ emb,
    const float* __restrict__ e2g, const s16x8* __restrict__ bfrag,
    float* __restrict__ out, float* __restrict__ wsum, int* __restrict__ whist)
{
    __shared__ float4 sx[RPB*17];    // 256 rows, padded stride 17 float4 (69632 B)
    __shared__ int    sidx[RPB];
    __shared__ int    shist[K];

    const int t = threadIdx.x;
    for (int i = t; i < K; i += TPB) shist[i] = 0;

    // stage 256 rows coalesced into padded LDS (16 float4 per thread)
    const float4* xin4 = reinterpret_cast<const float4*>(x) + (size_t)blockIdx.x * (RPB*16);
    for (int g = t; g < RPB*16; g += TPB)
        sx[(g >> 4)*17 + (g & 15)] = xin4[g];
    __syncthreads();

    const int l = t & 63, w = t >> 6;           // 4 waves
    const int q = l >> 4, r16 = l & 15;
    const int wbase = w * 64;                   // 64 rows per wave

    // A fragments: [mt][chunk][kstep], row = wbase+mt*16+r16, k = q*8+j+32*s
    s16x8 Af[4][3][2];
    #pragma unroll
    for (int mt = 0; mt < 4; ++mt) {
        #pragma unroll
        for (int s = 0; s < 2; ++s) {
            int rl = wbase + mt*16 + r16;
            float4 f0 = sx[rl*17 + q*2 + s*8];
            float4 f1 = sx[rl*17 + q*2 + s*8 + 1];
            split8(f0, f1, &Af[mt][0][s], &Af[mt][1][s], &Af[mt][2][s]);
        }
    }

    float bestd[4][4];
    int   besti[4][4];
    #pragma unroll
    for (int mt = 0; mt < 4; ++mt)
        #pragma unroll
        for (int g = 0; g < 4; ++g) { bestd[mt][g] = 3.4e38f; besti[mt][g] = 0; }

    const s16x8* bbase = bfrag + l;
    const f32x4 zero4 = {0.f,0.f,0.f,0.f};

    f32x4 accS0[4], accS1[4];                   // 8 chains, single set (32 regs)

    // B double-buffer (P even / Q odd tiles), distance-2 prefetch
    s16x8 p00,p01,p10,p11,p20,p21; float pe2;
    s16x8 q00,q01,q10,q11,q20,q21; float qe2;
    LOADB(p00,p01,p10,p11,p20,p21,pe2, 0);
    LOADB(q00,q01,q10,q11,q20,q21,qe2, 1);

    #pragma clang loop unroll(disable)
    for (int ct = 0; ct < 32; ct += 2) {
        TILE_MFMA_ALL(p00,p01,p10,p11,p20,p21, pe2);
        LOADB(p00,p01,p10,p11,p20,p21,pe2, (ct + 2) & 31);   // dead at ct=30, in-bounds
        TILE_ARGMIN_ALL(ct);
        TILE_MFMA_ALL(q00,q01,q10,q11,q20,q21, qe2);
        LOADB(q00,q01,q10,q11,q20,q21,qe2, (ct + 3) & 31);   // dead at ct=30, in-bounds
        TILE_ARGMIN_ALL(ct + 1);
    }

    // cross-lane argmin over the 16 cols held by lanes sharing q (bits 0-3)
    #pragma unroll
    for (int mask = 1; mask <= 8; mask <<= 1) {
        #pragma unroll
        for (int mt = 0; mt < 4; ++mt)
            #pragma unroll
            for (int g = 0; g < 4; ++g) {
                float od = __shfl_xor(bestd[mt][g], mask, 64);
                int   oi = __shfl_xor(besti[mt][g], mask, 64);
                if (od < bestd[mt][g] ||
                    (od == bestd[mt][g] && oi < besti[mt][g])) {
                    bestd[mt][g] = od; besti[mt][g] = oi;
                }
            }
    }
    if (r16 == 0) {
        #pragma unroll
        for (int mt = 0; mt < 4; ++mt)
            #pragma unroll
            for (int g = 0; g < 4; ++g)
                sidx[wbase + mt*16 + q*4 + g] = besti[mt][g];
    }
    __syncthreads();

    // fused epilogue: 1 thread per row, 64 elems (x from LDS, code from L2)
    const int row = t;
    const int grow = blockIdx.x * RPB + row;
    const int bi = sidx[row];
    float dsum = 0.f;
    {
        const float4* eq = reinterpret_cast<const float4*>(emb + (size_t)bi * D);
        float4* o = reinterpret_cast<float4*>(out + (size_t)grow * D);
        #pragma unroll
        for (int i = 0; i < 16; ++i) {
            float4 xv = sx[row*17 + i];
            float4 qv = eq[i];
            float4 v;
            float d0,d1,d2,d3;
            d0 = qv.x - xv.x; v.x = xv.x + d0; dsum = fmaf(d0,d0,dsum);
            d1 = qv.y - xv.y; v.y = xv.y + d1; dsum = fmaf(d1,d1,dsum);
            d2 = qv.z - xv.z; v.z = xv.z + d2; dsum = fmaf(d2,d2,dsum);
            d3 = qv.w - xv.w; v.w = xv.w + d3; dsum = fmaf(d3,d3,dsum);
            o[i] = v;
        }
    }
    out[IDX_OFF + grow] = (float)bi;
    atomicAdd(&shist[bi], 1);

    #pragma unroll
    for (int off = 32; off > 0; off >>= 1)
        dsum += __shfl_xor(dsum, off, 64);
    if ((t & 63) == 0)
        atomicAdd(wsum, dsum);

    __syncthreads();
    for (int i = t; i < K; i += TPB)
        if (shist[i]) atomicAdd(&whist[i], shist[i]);
}

__global__ __launch_bounds__(K) void vq_finalize(
    const float* __restrict__ wsum, const int* __restrict__ whist,
    float* __restrict__ out)
{
    __shared__ float red[K];
    int t = threadIdx.x;
    float c = (float)whist[t];
    float p = c / (float)NROWS;
    red[t] = p * logf(p + 1e-10f);
    __syncthreads();
    for (int s = K/2; s > 0; s >>= 1) {
        if (t < s) red[t] += red[t+s];
        __syncthreads();
    }
    if (t == 0) {
        out[PERP_OFF] = expf(-red[0]);
        out[LOSS_OFF] = 0.25f * (wsum[0] / (float)(NROWS*D));
    }
}

extern "C" void kernel_launch(void* const* d_in, const int* in_sizes, int n_in,
                              void* d_out, int out_size, void* d_ws, size_t ws_size,
                              hipStream_t stream)
{
    const float* x   = (const float*)d_in[0];
    const float* emb = (const float*)d_in[1];
    float* out   = (float*)d_out;
    float* wsum  = (float*)d_ws;                           // @0
    int*   whist = (int*)((char*)d_ws + 256);              // @256B
    float* e2    = (float*)((char*)d_ws + 4096);           // @4096B
    s16x8* bfrag = (s16x8*)((char*)d_ws + 8192);           // @8192B, 196608B

    hipMemsetAsync(d_ws, 0, 4096, stream);                 // zero wsum + hist
    vq_prep<<<32, 64, 0, stream>>>(emb, e2, bfrag);
    vq_main<<<NBLK, TPB, 0, stream>>>(x, emb, e2, bfrag, out, wsum, whist);
    vq_finalize<<<1, K, 0, stream>>>(wsum, whist, out);
}

// Round 13
// 92.230 us; speedup vs baseline: 1.3403x; 1.3403x over previous
//
#include <hip/hip_runtime.h>

#define NROWS 131072          // 64*2048
#define D 64
#define K 512
#define TPB 256               // 4 waves/block
#define RPB 128               // 4 waves x 32 rows (R10's proven-clean shape)
#define NBLK (NROWS/RPB)      // 1024

#define LOSS_OFF (NROWS*D)    // 8388608
#define PERP_OFF (LOSS_OFF+1)
#define IDX_OFF  (LOSS_OFF+2)

typedef _Float16 h16x8 __attribute__((ext_vector_type(8)));  // 8 fp16 (4 VGPR)
typedef float    f32x4 __attribute__((ext_vector_type(4)));  // MFMA acc

// ws: [0] f32 wsum | [256B] int hist[512] | [4096B] f32 e2[512] | [8192B] bfrag 131072B

// fp16 two-way split with scaled residual: v = h + 2^-12 * m', all operands
// normal-range fp16 (h self-flushed below 2^-14 so HW denorm policy is moot).
// Exact: hf->float exact; v-hf exact (Sterbenz); *4096 exact (pow2).
__device__ __forceinline__ void split8_f16(float4 a, float4 b,
                                           h16x8* h8, h16x8* m8)
{
    float xf[8] = {a.x,a.y,a.z,a.w,b.x,b.y,b.z,b.w};
    _Float16 hh[8], mm[8];
    #pragma unroll
    for (int j = 0; j < 8; ++j) {
        float v = xf[j];
        _Float16 h = (_Float16)v;                 // RTN
        float hf = (float)h;
        if (fabsf(hf) < 6.1035156e-5f) { h = (_Float16)0.f; hf = 0.f; }
        hh[j] = h;
        mm[j] = (_Float16)((v - hf) * 4096.f);    // m' = 2^12 * residual
    }
    *h8 = (h16x8){hh[0],hh[1],hh[2],hh[3],hh[4],hh[5],hh[6],hh[7]};
    *m8 = (h16x8){mm[0],mm[1],mm[2],mm[3],mm[4],mm[5],mm[6],mm[7]};
}

// prep: pack fp16 splits of (-2*codebook) into B-fragment order + fp32 e2.
// frag index per tile ct: 0: g(kstep0), 1: g(kstep1), 2: n'(kstep0), 3: n'(kstep1)
__global__ __launch_bounds__(64) void vq_prep(
    const float* __restrict__ emb, float* __restrict__ e2, h16x8* __restrict__ bfrag)
{
    const int ct = blockIdx.x, l = threadIdx.x;      // 32 blocks x 64
    const int q = l >> 4, r16 = l & 15;
    const int code = ct*16 + r16;
    const float4* e4 = reinterpret_cast<const float4*>(emb + (size_t)code * D);
    #pragma unroll
    for (int s = 0; s < 2; ++s) {
        float4 f0 = e4[q*2 + s*8];
        float4 f1 = e4[q*2 + s*8 + 1];
        float4 g0 = {-2.f*f0.x, -2.f*f0.y, -2.f*f0.z, -2.f*f0.w};
        float4 g1 = {-2.f*f1.x, -2.f*f1.y, -2.f*f1.z, -2.f*f1.w};
        h16x8 g, n;
        split8_f16(g0, g1, &g, &n);
        bfrag[(ct*4 + 0 + s)*64 + l] = g;
        bfrag[(ct*4 + 2 + s)*64 + l] = n;
    }
    if (l < 16) {
        const float* e = emb + (size_t)(ct*16 + l) * D;
        float s0=0.f,s1=0.f,s2=0.f,s3=0.f;
        #pragma unroll
        for (int d = 0; d < D; d += 4) {
            s0 = fmaf(e[d+0], e[d+0], s0);
            s1 = fmaf(e[d+1], e[d+1], s1);
            s2 = fmaf(e[d+2], e[d+2], s2);
            s3 = fmaf(e[d+3], e[d+3], s3);
        }
        e2[ct*16 + l] = (s0+s1)+(s2+s3);
    }
}

#define MFMA_(AV, BV, CI) __builtin_amdgcn_mfma_f32_16x16x32_f16((AV), (BV), (CI), 0, 0, 0)

// load B-fragment set for tile CT (4 frags + e2, stay in flight)
#define LOADB(B0,B1,B2,B3,E2V, CT) do {                             \
    const h16x8* _bp = bbase + (size_t)(CT)*4*64;                   \
    B0 = _bp[0*64]; B1 = _bp[1*64];                                 \
    B2 = _bp[2*64]; B3 = _bp[3*64];                                 \
    E2V = e2g[((CT) << 4) + r16];                                   \
} while (0)

// 12 MFMAs/tile: chainA = h.g (seeded e2), chainB = h.n' + m'.g (seeded 0),
// dist = A + 2^-12 * B.  4 round-robin chains, setprio around the cluster.
#define TILE_MFMA(SA0,SA1,SB0,SB1, B0,B1,B2,B3, E2V) do {            \
    f32x4 _ci = {(E2V),(E2V),(E2V),(E2V)};                           \
    __builtin_amdgcn_s_setprio(1);                                   \
    SA0 = MFMA_(Ah[0][0], B0, _ci);   SA1 = MFMA_(Ah[1][0], B0, _ci);  \
    SB0 = MFMA_(Ah[0][0], B2, zero4); SB1 = MFMA_(Ah[1][0], B2, zero4);\
    SA0 = MFMA_(Ah[0][1], B1, SA0);   SA1 = MFMA_(Ah[1][1], B1, SA1);  \
    SB0 = MFMA_(Am[0][0], B0, SB0);   SB1 = MFMA_(Am[1][0], B0, SB1);  \
    SB0 = MFMA_(Ah[0][1], B3, SB0);   SB1 = MFMA_(Ah[1][1], B3, SB1);  \
    SB0 = MFMA_(Am[0][1], B1, SB0);   SB1 = MFMA_(Am[1][1], B1, SB1);  \
    __builtin_amdgcn_s_setprio(0);                                   \
} while (0)

#define TILE_ARGMIN(SA0,SA1,SB0,SB1, CT) do {                                \
    const int _col = ((CT) << 4) + r16;                                      \
    _Pragma("unroll")                                                        \
    for (int g = 0; g < 4; ++g) {                                            \
        float dst0 = fmaf(SB0[g], 2.44140625e-4f, SA0[g]);                   \
        if (dst0 < bestd[0][g]) { bestd[0][g] = dst0; besti[0][g] = _col; }  \
        float dst1 = fmaf(SB1[g], 2.44140625e-4f, SA1[g]);                   \
        if (dst1 < bestd[1][g]) { bestd[1][g] = dst1; besti[1][g] = _col; }  \
    }                                                                        \
} while (0)

__global__ __launch_bounds__(TPB, 1) void vq_main(
    const float* __restrict__ x, const float* __restrict__ emb,
    const float* __restrict__ e2g, const h16x8* __restrict__ bfrag,
    float* __restrict__ out, float* __restrict__ wsum, int* __restrict__ whist)
{
    __shared__ float4 sx[RPB*17];    // 128 rows, padded stride 17 float4
    __shared__ int    sidx[RPB];
    __shared__ int    shist[K];

    const int t = threadIdx.x;
    for (int i = t; i < K; i += TPB) shist[i] = 0;

    // stage 128 rows coalesced into padded LDS
    const float4* xin4 = reinterpret_cast<const float4*>(x) + (size_t)blockIdx.x * (RPB*16);
    for (int g = t; g < RPB*16; g += TPB)
        sx[(g >> 4)*17 + (g & 15)] = xin4[g];
    __syncthreads();

    const int l = t & 63, w = t >> 6;
    const int q = l >> 4, r16 = l & 15;
    const int wbase = w * 32;

    // A fragments: [mt][kstep] for h and m', row = wbase+mt*16+r16, k = q*8+j+32*s
    h16x8 Ah[2][2], Am[2][2];
    #pragma unroll
    for (int mt = 0; mt < 2; ++mt) {
        #pragma unroll
        for (int s = 0; s < 2; ++s) {
            int rl = wbase + mt*16 + r16;
            float4 f0 = sx[rl*17 + q*2 + s*8];
            float4 f1 = sx[rl*17 + q*2 + s*8 + 1];
            split8_f16(f0, f1, &Ah[mt][s], &Am[mt][s]);
        }
    }

    float bestd[2][4];
    int   besti[2][4];
    #pragma unroll
    for (int mt = 0; mt < 2; ++mt)
        #pragma unroll
        for (int g = 0; g < 4; ++g) { bestd[mt][g] = 3.4e38f; besti[mt][g] = 0; }

    const h16x8* bbase = bfrag + l;
    const f32x4 zero4 = {0.f,0.f,0.f,0.f};

    // B double-buffer (P even / Q odd tiles) + acc double-buffer (E/O sets)
    h16x8 p0,p1,p2,p3; float pe2;
    h16x8 q0,q1,q2,q3; float qe2;
    f32x4 eA0,eA1,eB0,eB1;   // even-tile acc set
    f32x4 oA0,oA1,oB0,oB1;   // odd-tile acc set

    LOADB(p0,p1,p2,p3,pe2, 0);
    LOADB(q0,q1,q2,q3,qe2, 1);
    TILE_MFMA(eA0,eA1,eB0,eB1, p0,p1,p2,p3, pe2);
    LOADB(p0,p1,p2,p3,pe2, 2);

    #pragma clang loop unroll(disable)
    for (int ct = 1; ct < 31; ct += 2) {
        TILE_MFMA(oA0,oA1,oB0,oB1, q0,q1,q2,q3, qe2);
        LOADB(q0,q1,q2,q3,qe2, ct + 2);
        TILE_ARGMIN(eA0,eA1,eB0,eB1, ct - 1);
        TILE_MFMA(eA0,eA1,eB0,eB1, p0,p1,p2,p3, pe2);
        LOADB(p0,p1,p2,p3,pe2, (ct + 3) & 31);  // 32->0 dead load, in-bounds
        TILE_ARGMIN(oA0,oA1,oB0,oB1, ct);
    }
    TILE_MFMA(oA0,oA1,oB0,oB1, q0,q1,q2,q3, qe2);   // tile 31
    TILE_ARGMIN(eA0,eA1,eB0,eB1, 30);
    TILE_ARGMIN(oA0,oA1,oB0,oB1, 31);

    // cross-lane argmin over the 16 cols held by lanes sharing q (bits 0-3)
    #pragma unroll
    for (int mask = 1; mask <= 8; mask <<= 1) {
        #pragma unroll
        for (int mt = 0; mt < 2; ++mt)
            #pragma unroll
            for (int g = 0; g < 4; ++g) {
                float od = __shfl_xor(bestd[mt][g], mask, 64);
                int   oi = __shfl_xor(besti[mt][g], mask, 64);
                if (od < bestd[mt][g] ||
                    (od == bestd[mt][g] && oi < besti[mt][g])) {
                    bestd[mt][g] = od; besti[mt][g] = oi;
                }
            }
    }
    if (r16 == 0) {
        #pragma unroll
        for (int mt = 0; mt < 2; ++mt)
            #pragma unroll
            for (int g = 0; g < 4; ++g)
                sidx[wbase + mt*16 + q*4 + g] = besti[mt][g];
    }
    __syncthreads();

    // fused epilogue: 2 threads per row, 32 elems each (x from LDS, code from L2)
    const int row = t >> 1, half = t & 1;
    const int grow = blockIdx.x * RPB + row;
    const int bi = sidx[row];
    float dsum = 0.f;
    {
        const float4* eq = reinterpret_cast<const float4*>(emb + (size_t)bi * D) + half*8;
        float4* o = reinterpret_cast<float4*>(out + (size_t)grow * D) + half*8;
        #pragma unroll
        for (int i = 0; i < 8; ++i) {
            float4 xv = sx[row*17 + half*8 + i];
            float4 qv = eq[i];
            float4 v;
            float d0,d1,d2,d3;
            d0 = qv.x - xv.x; v.x = xv.x + d0; dsum = fmaf(d0,d0,dsum);
            d1 = qv.y - xv.y; v.y = xv.y + d1; dsum = fmaf(d1,d1,dsum);
            d2 = qv.z - xv.z; v.z = xv.z + d2; dsum = fmaf(d2,d2,dsum);
            d3 = qv.w - xv.w; v.w = xv.w + d3; dsum = fmaf(d3,d3,dsum);
            o[i] = v;
        }
    }
    if (half == 0) {
        out[IDX_OFF + grow] = (float)bi;
        atomicAdd(&shist[bi], 1);
    }

    #pragma unroll
    for (int off = 32; off > 0; off >>= 1)
        dsum += __shfl_xor(dsum, off, 64);
    if ((t & 63) == 0)
        atomicAdd(wsum, dsum);

    __syncthreads();
    for (int i = t; i < K; i += TPB)
        if (shist[i]) atomicAdd(&whist[i], shist[i]);
}

__global__ __launch_bounds__(K) void vq_finalize(
    const float* __restrict__ wsum, const int* __restrict__ whist,
    float* __restrict__ out)
{
    __shared__ float red[K];
    int t = threadIdx.x;
    float c = (float)whist[t];
    float p = c / (float)NROWS;
    red[t] = p * logf(p + 1e-10f);
    __syncthreads();
    for (int s = K/2; s > 0; s >>= 1) {
        if (t < s) red[t] += red[t+s];
        __syncthreads();
    }
    if (t == 0) {
        out[PERP_OFF] = expf(-red[0]);
        out[LOSS_OFF] = 0.25f * (wsum[0] / (float)(NROWS*D));
    }
}

extern "C" void kernel_launch(void* const* d_in, const int* in_sizes, int n_in,
                              void* d_out, int out_size, void* d_ws, size_t ws_size,
                              hipStream_t stream)
{
    const float* x   = (const float*)d_in[0];
    const float* emb = (const float*)d_in[1];
    float* out   = (float*)d_out;
    float* wsum  = (float*)d_ws;                           // @0
    int*   whist = (int*)((char*)d_ws + 256);              // @256B
    float* e2    = (float*)((char*)d_ws + 4096);           // @4096B
    h16x8* bfrag = (h16x8*)((char*)d_ws + 8192);           // @8192B, 131072B

    hipMemsetAsync(d_ws, 0, 4096, stream);                 // zero wsum + hist
    vq_prep<<<32, 64, 0, stream>>>(emb, e2, bfrag);
    vq_main<<<NBLK, TPB, 0, stream>>>(x, emb, e2, bfrag, out, wsum, whist);
    vq_finalize<<<1, K, 0, stream>>>(wsum, whist, out);
}